// Round 18
// baseline (55.961 us; speedup 1.0000x reference)
//
#include <hip/hip_runtime.h>
#include <hip/hip_bf16.h>
#include <stdint.h>

#define BB    8
#define NN    4096
#define FIN   32
#define FF    33         // FIN + 1 noise channel
#define KPAD  64         // feature dim padded; dims 33,34 carry the threshold fold
#define NQ    (BB*NN)    // 32768 query points
#define NTRI  136        // 16*17/2 slab pairs (qt <= ms), 256-row q-slabs

// Sieve: d2 < 14 (dropped survivors weigh <= e^-14; r8 confirmed absmax 9.8e-4).
// Augmentation: fbA[33]=3.5-sq/2, fbA[34]=1 ; fbB[33]=1, fbB[34]=3.5-sq/2
// => acc = dot - 0.5*sq_n - 0.5*sq_m + 7 ; acc > 0 <=> d2 < 14
//
// r17 post-mortem: knn ~28us vs ~2us issue floor. The exposed latency is the
// RETURNING atomicAdd (pos -> dependent store, ~400cy L2 round-trip on the
// critical path, ~17 hit-tiles/wave ~ 7k cy). This round: neighbor BITMASK via
// fire-and-forget atomicOr (no result -> no waitcnt consumer). Gather
// enumerates mask via ballot/ffsll ascending (deterministic), 2 queries/wave.
// prep: 4 lanes/row (512->2048 waves) + folds the 16MB mask clear (no launch).

// ---- mask path: ~24.2 MB ----
#define OFF_FBA    0ull
#define OFF_FBB    (OFF_FBA  + (size_t)NQ*KPAD*2)     // +4 MB
#define OFF_MASK   (OFF_FBB  + (size_t)NQ*KPAD*2)     // +4 MB
#define OFF_PART   (OFF_MASK + (size_t)NQ*64*8)       // +16 MB
#define WS_NEED    (OFF_PART + (size_t)(NQ/8)*4)

typedef short short8 __attribute__((ext_vector_type(8)));
typedef float floatx4 __attribute__((ext_vector_type(4)));

// ---------------- prep: 4 lanes/row; augmented bf16 rows; mask clear fused ----------------
// XCD-pinned: bb = blockIdx & 7. Block = 64 rows x 4 lanes.
__global__ __launch_bounds__(256) void prep_kernel(const float* __restrict__ x,
                                                   const float* __restrict__ noise,
                                                   unsigned short* __restrict__ fbA,
                                                   unsigned short* __restrict__ fbB,
                                                   unsigned long long* __restrict__ mask) {
    int bb  = blockIdx.x & 7;
    int jb  = blockIdx.x >> 3;           // 0..63 within batch
    int rib = threadIdx.x >> 2;          // row in block 0..63
    int jl  = threadIdx.x & 3;           // lane-in-row 0..3
    int q   = bb * NN + jb * 64 + rib;

    // clear this thread's slice of q's neighbor mask (16 u64 = 8 uint4)
    uint4* mw = (uint4*)(mask + (size_t)q * 64 + jl * 16);
    const uint4 z = {0, 0, 0, 0};
#pragma unroll
    for (int i = 0; i < 8; ++i) mw[i] = z;

    // lane jl owns output dims [16*jl, 16*jl+16)
    float v[16];
    float s = 0.f;
    if (jl < 2) {                        // dims 0-15 / 16-31 from x
        const float4* xr = (const float4*)(x + (size_t)q * FIN + jl * 16);
#pragma unroll
        for (int i = 0; i < 4; ++i) {
            float4 t = xr[i];
            v[i*4+0] = t.x; v[i*4+1] = t.y; v[i*4+2] = t.z; v[i*4+3] = t.w;
        }
#pragma unroll
        for (int d = 0; d < 16; ++d) s += v[d] * v[d];
    } else {
#pragma unroll
        for (int d = 0; d < 16; ++d) v[d] = 0.f;
    }
    float nz = 0.f;
    if (jl == 2) { nz = noise[q]; s = nz * nz; }
    s += __shfl_xor(s, 1);               // reduce sq over the 4-lane group
    s += __shfl_xor(s, 2);

    unsigned short rowA[16], rowB[16];
#pragma unroll
    for (int d = 0; d < 16; ++d) {
        __hip_bfloat16 h = __float2bfloat16(v[d]);
        unsigned short u = *(unsigned short*)&h;
        rowA[d] = u; rowB[d] = u;
    }
    if (jl == 2) {                       // dims 32(noise), 33, 34
        __hip_bfloat16 hn = __float2bfloat16(nz);
        unsigned short un = *(unsigned short*)&hn;
        __hip_bfloat16 hs = __float2bfloat16(3.5f - 0.5f * s);   // THR/4 - sq/2
        unsigned short us = *(unsigned short*)&hs;
        const unsigned short one = 0x3F80;   // bf16 1.0
        rowA[0] = un; rowA[1] = us;  rowA[2] = one;
        rowB[0] = un; rowB[1] = one; rowB[2] = us;
    }
    uint4* dA = (uint4*)(fbA + (size_t)q * KPAD + jl * 16);
    uint4* dB = (uint4*)(fbB + (size_t)q * KPAD + jl * 16);
    dA[0] = ((const uint4*)rowA)[0]; dA[1] = ((const uint4*)rowA)[1];
    dB[0] = ((const uint4*)rowB)[0]; dB[1] = ((const uint4*)rowB)[1];
}

// ---------------- phase 1: symmetric MFMA sieve -> bitmask, fire-and-forget atomicOr ----------------
// XCD-pinned (blockIdx&7 = batch). Triangle (qt<=ms, msub): q-slab 256 (wave =
// 4 A-tiles), m-range 128 (8 tiles ALL preloaded -> 16 loads in flight).
__global__ __launch_bounds__(256) void knn_kernel(const unsigned short* __restrict__ fbA,
                                                  const unsigned short* __restrict__ fbB,
                                                  unsigned long long* __restrict__ mask) {
    int bb  = blockIdx.x & 7;
    int rem = blockIdx.x >> 3;           // 0..271 pair index
    int tri = rem >> 1, msub = rem & 1;
    int t = tri, qt = 0;
    while (t >= 16 - qt) { t -= 16 - qt; ++qt; }
    int ms = qt + t;

    int wid = threadIdx.x >> 6, lane = threadIdx.x & 63;
    int qb  = qt * 256 + wid * 64;       // wave's query base (batch-local)
    int mstart = ms * 256 + msub * 128;
    if (mstart + 128 <= qb) return;      // wave entirely below diagonal: no work

    int g16 = lane >> 4, l16 = lane & 15;
    size_t base = (size_t)bb * NN;

    short8 a0[4], a1[4];                 // 4 A-tiles (32 VGPR)
#pragma unroll
    for (int a = 0; a < 4; ++a) {
        const short8* pA = (const short8*)fbA + ((base + qb + a * 16 + l16) * 8 + g16);
        a0[a] = pA[0];
        a1[a] = pA[4];   // k += 32
    }

    const short8* pB = (const short8*)fbB + ((base + mstart + l16) * 8 + g16);
    short8 b0[8], b1[8];                 // ALL 8 m-tiles preloaded
#pragma unroll
    for (int mt = 0; mt < 8; ++mt) {
        b0[mt] = pB[mt * 128];
        b1[mt] = pB[mt * 128 + 4];
    }

#pragma unroll
    for (int mt = 0; mt < 8; ++mt) {
        int mb = mstart + mt * 16;
        if (mb + 16 > qb) {              // skip tiles fully below the wave's diagonal
            int m = mb + l16;
#pragma unroll
            for (int a = 0; a < 4; ++a) {
                floatx4 acc = {0.f, 0.f, 0.f, 0.f};
                acc = __builtin_amdgcn_mfma_f32_16x16x32_bf16(a0[a], b0[mt], acc, 0, 0, 0);
                acc = __builtin_amdgcn_mfma_f32_16x16x32_bf16(a1[a], b1[mt], acc, 0, 0, 0);
                float mm = fmaxf(fmaxf(acc[0], acc[1]), fmaxf(acc[2], acc[3]));
                if (mm > 0.f) {
#pragma unroll
                    for (int r = 0; r < 4; ++r) {
                        int n = qb + a * 16 + g16 * 4 + r;   // C/D row = (lane>>4)*4 + reg
                        if (acc[r] > 0.f && m > n) {
                            // fire-and-forget: result unused -> no waitcnt dependency
                            atomicOr(&mask[(base + n) * 64 + (m >> 6)], 1ull << (m & 63));
                            atomicOr(&mask[(base + m) * 64 + (n >> 6)], 1ull << (n & 63));
                        }
                    }
                }
            }
        }
    }
}

// ---------------- phase 2: mask enumeration, 2 queries/wave, fused head ----------------
// Lanes 0-31 = q0, 32-63 = q1. Lane hl holds mask words 2hl,2hl+1 (one uint4).
// Ballot/ffs extraction -> ascending m order -> deterministic.
__global__ __launch_bounds__(256) void gather_kernel(const float* __restrict__ x,
                                                     const float* __restrict__ noise,
                                                     const float* __restrict__ y,
                                                     const float* __restrict__ W1,
                                                     const float* __restrict__ b1,
                                                     const unsigned long long* __restrict__ mask,
                                                     float* __restrict__ out,
                                                     float* __restrict__ partials) {
    __shared__ float e_lds[8][2 * FF];
    __shared__ float msep[8];
    int bb = blockIdx.x & 7;
    int j  = blockIdx.x >> 3;
    int q0blk = bb * NN + j * 8;
    int wid = threadIdx.x >> 6, lane = threadIdx.x & 63;
    int hf = lane >> 5, hl = lane & 31;           // half index, lane-in-half
    int q  = q0blk + wid * 2 + hf;
    size_t base = (size_t)bb * NN;

    float fnd  = x[(size_t)q * FIN + hl];
    float fnd2 = (hl == 0) ? noise[q] : 0.f;      // d=32 slot

    uint4 mv = ((const uint4*)(mask + (size_t)q * 64))[hl];
    unsigned long long w0 = ((unsigned long long)mv.y << 32) | mv.x;   // word 2hl
    unsigned long long w1 = ((unsigned long long)mv.w << 32) | mv.z;   // word 2hl+1

    float den = 1.f, num = 0.f, num2 = 0.f;       // self: w=1, diff=0
    for (;;) {
        unsigned long long bal = __ballot((w0 | w1) != 0ull);
        if (bal == 0ull) break;
        unsigned int hm = (unsigned int)(bal >> (hf << 5));
        bool act = (hm != 0u);
        int L = __ffs(hm) - 1;                    // lowest lane-in-half with bits
        int src = (hf << 5) + (act ? L : 0);
        unsigned long long v0 = __shfl(w0, src);
        unsigned long long v1 = __shfl(w1, src);
        int word = (v0 != 0ull) ? 0 : 1;
        unsigned long long bits = (v0 != 0ull) ? v0 : v1;
        int b = __ffsll((long long)bits) - 1;
        int m = act ? (L * 128 + word * 64 + b) : 0;
        if (act && hl == L) {                     // owner clears the extracted bit
            if (word == 0) w0 &= w0 - 1ull; else w1 &= w1 - 1ull;
        }
        float fm  = x[(base + m) * (size_t)FIN + hl];
        float fm2 = (hl == 0) ? noise[base + m] : 0.f;
        float diff  = fm - fnd;
        float diff2 = fm2 - fnd2;
        float s = diff * diff + diff2 * diff2;
#pragma unroll
        for (int off = 16; off; off >>= 1) s += __shfl_xor(s, off);
        float wgt = act ? __expf(-s) : 0.f;       // exact fp32 d2
        den += wgt;
        num += wgt * diff;
        num2 += wgt * diff2;
    }
    float md = num / den, md2 = num2 / den;       // den >= 1 always

    int qs = wid * 2 + hf;                        // 0..7 query slot in block
    e_lds[qs][hl]      = fnd;
    e_lds[qs][FF + hl] = md;
    if (hl == 0) { e_lds[qs][32] = fnd2; e_lds[qs][FF + 32] = md2; }
    __syncthreads();

    // head: thread = (query hq, channel ch); 8 x 32 = 256
    int hq = threadIdx.x >> 5, ch = threadIdx.x & 31;
    int qq = q0blk + hq;
    float g0 = b1[ch], g1 = 0.f;                  // split dependent chain
#pragma unroll
    for (int e = 0; e < 2 * FF; e += 2) {
        g0 = fmaf(e_lds[hq][e],     W1[e * FIN + ch],       g0);
        g1 = fmaf(e_lds[hq][e + 1], W1[(e + 1) * FIN + ch], g1);
    }
    float g = fmaxf(g0 + g1, 0.f);
    out[(size_t)qq * FIN + ch] = g;
    float tt = g - y[(size_t)qq * FIN + ch];
    float d = tt * tt;
#pragma unroll
    for (int off = 16; off; off >>= 1) d += __shfl_xor(d, off);
    if (ch == 0) msep[hq] = d;
    __syncthreads();
    if (threadIdx.x == 0) {
        float a = 0.f;
#pragma unroll
        for (int i = 0; i < 8; ++i) a += msep[i];
        partials[blockIdx.x] = a;
    }
}

// ---------------- phase 2 (brute, ws-too-small last resort) ----------------
__global__ __launch_bounds__(256) void gather_brute(const float* __restrict__ x,
                                                    const float* __restrict__ noise,
                                                    const float* __restrict__ y,
                                                    const float* __restrict__ W1,
                                                    const float* __restrict__ b1,
                                                    float* __restrict__ out,
                                                    float* __restrict__ partials) {
    __shared__ float e_lds[4][2 * FF];
    __shared__ float msep[4];
    int wid = threadIdx.x >> 6, lane = threadIdx.x & 63;
    int q = blockIdx.x * 4 + wid;
    int bb = q >> 12;
    int nloc = q & (NN - 1);
    size_t base = (size_t)bb * NN;

    float fnd = 0.f;
    if (lane < FIN)          fnd = x[(size_t)q * FIN + lane];
    else if (lane == FF - 1) fnd = noise[q];

    float den = 1.f, num = 0.f;
    for (int m = 0; m < NN; ++m) {
        if (m == nloc) continue;
        float fmd = 0.f;
        if (lane < FIN)          fmd = x[(base + m) * (size_t)FIN + lane];
        else if (lane == FF - 1) fmd = noise[base + m];
        float diff = (lane < FF) ? (fmd - fnd) : 0.f;
        float s = diff * diff;
#pragma unroll
        for (int off = 32; off; off >>= 1) s += __shfl_xor(s, off);
        float w = __expf(-s);
        den += w;
        num += w * diff;
    }
    float md = num / den;

    if (lane < FF) { e_lds[wid][lane] = fnd; e_lds[wid][FF + lane] = md; }
    __syncthreads();
    float g = 0.f;
    if (lane < FIN) {
        g = b1[lane];
#pragma unroll
        for (int e = 0; e < 2 * FF; ++e)
            g = fmaf(e_lds[wid][e], W1[e * FIN + lane], g);
        g = fmaxf(g, 0.f);
        out[(size_t)q * FIN + lane] = g;
    }
    float d = 0.f;
    if (lane < FIN) {
        float t = g - y[(size_t)q * FIN + lane];
        d = t * t;
    }
#pragma unroll
    for (int off = 32; off; off >>= 1) d += __shfl_xor(d, off);
    if (lane == 0) msep[wid] = d;
    __syncthreads();
    if (threadIdx.x == 0)
        partials[blockIdx.x] = msep[0] + msep[1] + msep[2] + msep[3];
}

// ---------------- final: gen_mse (n4 = partial count / 4) ----------------
__global__ __launch_bounds__(256) void reduce_kernel(const float* __restrict__ partials,
                                                     float* __restrict__ out, int n4) {
    __shared__ float sw[4];
    int wid = threadIdx.x >> 6, lane = threadIdx.x & 63;
    const float4* p4 = (const float4*)partials;
    float ax = 0.f, ay = 0.f, az = 0.f, aw = 0.f;
    for (int i = threadIdx.x; i < n4; i += 256) {
        float4 v = p4[i];
        ax += v.x; ay += v.y; az += v.z; aw += v.w;
    }
    float a = (ax + ay) + (az + aw);
#pragma unroll
    for (int off = 32; off; off >>= 1) a += __shfl_xor(a, off);
    if (lane == 0) sw[wid] = a;
    __syncthreads();
    if (threadIdx.x == 0)
        out[(size_t)NQ * FIN] = (sw[0] + sw[1] + sw[2] + sw[3]) / (float)((size_t)NQ * FIN);
}

extern "C" void kernel_launch(void* const* d_in, const int* in_sizes, int n_in,
                              void* d_out, int out_size, void* d_ws, size_t ws_size,
                              hipStream_t stream) {
    const float* x     = (const float*)d_in[0];
    const float* noise = (const float*)d_in[1];
    const float* y     = (const float*)d_in[2];
    const float* W1    = (const float*)d_in[3];
    const float* b1    = (const float*)d_in[4];
    float* out = (float*)d_out;
    char* ws = (char*)d_ws;

    if (ws_size >= WS_NEED) {
        unsigned short* fbA = (unsigned short*)(ws + OFF_FBA);
        unsigned short* fbB = (unsigned short*)(ws + OFF_FBB);
        unsigned long long* mask = (unsigned long long*)(ws + OFF_MASK);
        float* partial = (float*)(ws + OFF_PART);

        prep_kernel<<<NQ / 64, 256, 0, stream>>>(x, noise, fbA, fbB, mask);
        knn_kernel<<<BB * NTRI * 2, 256, 0, stream>>>(fbA, fbB, mask);
        gather_kernel<<<NQ / 8, 256, 0, stream>>>(x, noise, y, W1, b1, mask, out, partial);
        reduce_kernel<<<1, 256, 0, stream>>>(partial, out, (NQ / 8) / 4);
    } else {
        float* partial = (float*)ws;
        gather_brute<<<NQ / 4, 256, 0, stream>>>(x, noise, y, W1, b1, out, partial);
        reduce_kernel<<<1, 256, 0, stream>>>(partial, out, (NQ / 4) / 4);
    }
}